// Round 1
// baseline (262.656 us; speedup 1.0000x reference)
//
#include <hip/hip_runtime.h>

typedef unsigned short u16;
typedef __attribute__((ext_vector_type(8))) short bf16x8;
typedef __attribute__((ext_vector_type(4))) float f32x4;
typedef __attribute__((ext_vector_type(4))) unsigned short u16x4;

#define MFMA __builtin_amdgcn_mfma_f32_16x16x32_bf16

__device__ __forceinline__ u16 f2bf(float f) {
  unsigned int u = __float_as_uint(f);
  u += 0x7fff + ((u >> 16) & 1);          // round-to-nearest-even
  return (u16)(u >> 16);
}

__device__ __forceinline__ void gload_lds16(const void* g, void* l) {
  __builtin_amdgcn_global_load_lds((__attribute__((address_space(1))) void*)g,
                                   (__attribute__((address_space(3))) void*)l,
                                   16, 0, 0);
}

// ---------------- cast x (fp32 -> bf16), 4 elems/thread ----------------
__global__ void k_cast(const float* __restrict__ src, u16* __restrict__ dst, int n4) {
  int i = blockIdx.x * 256 + threadIdx.x;
  if (i >= n4) return;
  const float4 v = reinterpret_cast<const float4*>(src)[i];
  u16x4 o = {f2bf(v.x), f2bf(v.y), f2bf(v.z), f2bf(v.w)};
  reinterpret_cast<u16x4*>(dst)[i] = o;
}

// ------- transpose+cast weights: src fp32 [R][C] -> dst bf16 [C][R] -------
__global__ void k_transpose_cast(const float* __restrict__ src, u16* __restrict__ dst,
                                 int R, int C) {
  __shared__ float tile[64][65];
  const int t = threadIdx.x;
  const int c0 = blockIdx.x * 64, r0 = blockIdx.y * 64;
#pragma unroll
  for (int i = 0; i < 16; ++i) {
    int e = i * 256 + t;
    int r = e >> 6, c = e & 63;
    tile[r][c] = src[(size_t)(r0 + r) * C + (c0 + c)];
  }
  __syncthreads();
#pragma unroll
  for (int i = 0; i < 16; ++i) {
    int e = i * 256 + t;
    int r = e >> 6, c = e & 63;
    dst[(size_t)(c0 + r) * R + (r0 + c)] = f2bf(tile[c][r]);
  }
}

// ---------------- qkv GEMM: [4096,1280] x [3840,1280]^T + bias ----------------
// 128x128 tile, BK=64, 4 waves 2x2, each wave 64x64 (4x4 of 16x16x32 MFMA)
__global__ __launch_bounds__(256, 2) void k_gemm_qkv(
    const u16* __restrict__ A, const u16* __restrict__ Bt,
    const float* __restrict__ bias,
    u16* __restrict__ qo, u16* __restrict__ ko, u16* __restrict__ vo) {
  constexpr int K = 1280;
  __shared__ u16 Alds[128 * 64];
  __shared__ u16 Blds[128 * 64];
  const int t = threadIdx.x;
  const int lane = t & 63, wave = t >> 6;
  const int wr = wave >> 1, wc = wave & 1;
  const int l15 = lane & 15, lhi = lane >> 4;
  const int m0 = blockIdx.x * 128, n0 = blockIdx.y * 128;

  f32x4 acc[4][4];
#pragma unroll
  for (int mi = 0; mi < 4; ++mi)
#pragma unroll
    for (int ni = 0; ni < 4; ++ni) acc[mi][ni] = f32x4{0.f, 0.f, 0.f, 0.f};

  const int srow = t >> 3;
  const int scol = (t & 7) * 8;
  const u16* Ag = A + (size_t)(m0 + srow) * K + scol;
  const u16* Bg = Bt + (size_t)(n0 + srow) * K + scol;
  char* Al = (char*)Alds + wave * 1024;
  char* Bl = (char*)Blds + wave * 1024;

  for (int k0 = 0; k0 < K; k0 += 64) {
    __syncthreads();
#pragma unroll
    for (int it = 0; it < 4; ++it) {
      gload_lds16(Ag + (it * 32) * K + k0, Al + it * 4096);
      gload_lds16(Bg + (it * 32) * K + k0, Bl + it * 4096);
    }
    asm volatile("s_waitcnt vmcnt(0)" ::: "memory");
    __syncthreads();
    const u16* Ab = Alds + (wr * 64 + l15) * 64 + lhi * 8;
    const u16* Bb = Blds + (wc * 64 + l15) * 64 + lhi * 8;
    bf16x8 af[4][2], bfv[4][2];
#pragma unroll
    for (int x = 0; x < 4; ++x) {
      af[x][0] = *(const bf16x8*)(Ab + x * 1024);
      af[x][1] = *(const bf16x8*)(Ab + x * 1024 + 32);
      bfv[x][0] = *(const bf16x8*)(Bb + x * 1024);
      bfv[x][1] = *(const bf16x8*)(Bb + x * 1024 + 32);
    }
#pragma unroll
    for (int mi = 0; mi < 4; ++mi)
#pragma unroll
      for (int ni = 0; ni < 4; ++ni) {
        acc[mi][ni] = MFMA(af[mi][0], bfv[ni][0], acc[mi][ni], 0, 0, 0);
        acc[mi][ni] = MFMA(af[mi][1], bfv[ni][1], acc[mi][ni], 0, 0, 0);
      }
  }

  // epilogue: bias + scatter into q/k/v [B=2, h=20, S=2048, d=64] bf16
  const int which = n0 >= 2560 ? 2 : (n0 >= 1280 ? 1 : 0);
  u16* outp = which == 0 ? qo : (which == 1 ? ko : vo);
#pragma unroll
  for (int ni = 0; ni < 4; ++ni) {
    const int n_abs = n0 + wc * 64 + ni * 16 + l15;
    const int nn = n_abs - which * 1280;
    const int h = nn >> 6, d = nn & 63;
    const float bv = bias[n_abs];
#pragma unroll
    for (int mi = 0; mi < 4; ++mi) {
#pragma unroll
      for (int i = 0; i < 4; ++i) {
        const int m_abs = m0 + wr * 64 + mi * 16 + lhi * 4 + i;
        const int bb = m_abs >> 11, ss = m_abs & 2047;
        outp[(((size_t)(bb * 20 + h) * 2048 + ss) << 6) + d] = f2bf(acc[mi][ni][i] + bv);
      }
    }
  }
}

// ---------------- proj GEMM: [4096,1280] x [1280,1280]^T + bias -> fp32 ----------------
__global__ __launch_bounds__(256, 2) void k_gemm_proj(
    const u16* __restrict__ A, const u16* __restrict__ Bt,
    const float* __restrict__ bias, float* __restrict__ out) {
  constexpr int K = 1280;
  __shared__ u16 Alds[128 * 64];
  __shared__ u16 Blds[128 * 64];
  const int t = threadIdx.x;
  const int lane = t & 63, wave = t >> 6;
  const int wr = wave >> 1, wc = wave & 1;
  const int l15 = lane & 15, lhi = lane >> 4;
  const int m0 = blockIdx.x * 128, n0 = blockIdx.y * 128;

  f32x4 acc[4][4];
#pragma unroll
  for (int mi = 0; mi < 4; ++mi)
#pragma unroll
    for (int ni = 0; ni < 4; ++ni) acc[mi][ni] = f32x4{0.f, 0.f, 0.f, 0.f};

  const int srow = t >> 3;
  const int scol = (t & 7) * 8;
  const u16* Ag = A + (size_t)(m0 + srow) * K + scol;
  const u16* Bg = Bt + (size_t)(n0 + srow) * K + scol;
  char* Al = (char*)Alds + wave * 1024;
  char* Bl = (char*)Blds + wave * 1024;

  for (int k0 = 0; k0 < K; k0 += 64) {
    __syncthreads();
#pragma unroll
    for (int it = 0; it < 4; ++it) {
      gload_lds16(Ag + (it * 32) * K + k0, Al + it * 4096);
      gload_lds16(Bg + (it * 32) * K + k0, Bl + it * 4096);
    }
    asm volatile("s_waitcnt vmcnt(0)" ::: "memory");
    __syncthreads();
    const u16* Ab = Alds + (wr * 64 + l15) * 64 + lhi * 8;
    const u16* Bb = Blds + (wc * 64 + l15) * 64 + lhi * 8;
    bf16x8 af[4][2], bfv[4][2];
#pragma unroll
    for (int x = 0; x < 4; ++x) {
      af[x][0] = *(const bf16x8*)(Ab + x * 1024);
      af[x][1] = *(const bf16x8*)(Ab + x * 1024 + 32);
      bfv[x][0] = *(const bf16x8*)(Bb + x * 1024);
      bfv[x][1] = *(const bf16x8*)(Bb + x * 1024 + 32);
    }
#pragma unroll
    for (int mi = 0; mi < 4; ++mi)
#pragma unroll
      for (int ni = 0; ni < 4; ++ni) {
        acc[mi][ni] = MFMA(af[mi][0], bfv[ni][0], acc[mi][ni], 0, 0, 0);
        acc[mi][ni] = MFMA(af[mi][1], bfv[ni][1], acc[mi][ni], 0, 0, 0);
      }
  }

#pragma unroll
  for (int ni = 0; ni < 4; ++ni) {
    const int n_abs = n0 + wc * 64 + ni * 16 + l15;
    const float bv = bias[n_abs];
#pragma unroll
    for (int mi = 0; mi < 4; ++mi) {
#pragma unroll
      for (int i = 0; i < 4; ++i) {
        const int m_abs = m0 + wr * 64 + mi * 16 + lhi * 4 + i;
        out[(size_t)m_abs * 1280 + n_abs] = acc[mi][ni][i] + bv;
      }
    }
  }
}

// ---------------- causal flash attention ----------------
// grid (16 q-tiles, 40 bh). 4 waves x 32 q-rows. KVBLK=64.
__global__ __launch_bounds__(256, 2) void k_attn(
    const u16* __restrict__ Q, const u16* __restrict__ Kt,
    const u16* __restrict__ V, u16* __restrict__ ao) {
  __shared__ u16 Klds[64 * 72];
  __shared__ u16 Vt[64 * 72];
  __shared__ u16 Plds[4 * 32 * 72];
  const int t = threadIdx.x;
  const int lane = t & 63, wave = t >> 6;
  const int l15 = lane & 15, lhi = lane >> 4;
  const int qt = blockIdx.x, bh = blockIdx.y;
  const int bb = bh / 20, hh = bh % 20;
  const size_t base = (size_t)bh * 2048 * 64;
  const u16* Qp = Q + base;
  const u16* Kp = Kt + base;
  const u16* Vp = V + base;
  const int q0w = qt * 128 + wave * 32;

  // Q fragments live in registers for the whole kernel
  bf16x8 qf[2][2];
#pragma unroll
  for (int mr = 0; mr < 2; ++mr)
#pragma unroll
    for (int kk = 0; kk < 2; ++kk)
      qf[mr][kk] = *(const bf16x8*)(Qp + (q0w + mr * 16 + l15) * 64 + kk * 32 + lhi * 8);

  f32x4 o[2][4];
  float mrun[2][4], lrun[2][4];
#pragma unroll
  for (int mr = 0; mr < 2; ++mr) {
#pragma unroll
    for (int i = 0; i < 4; ++i) { mrun[mr][i] = -1e30f; lrun[mr][i] = 0.f; }
#pragma unroll
    for (int dc = 0; dc < 4; ++dc) o[mr][dc] = f32x4{0.f, 0.f, 0.f, 0.f};
  }

  const int nkv = (qt + 1) * 2;
  const int sr = t >> 2, sc4 = (t & 3) * 16;
  u16* Pw = Plds + wave * (32 * 72);

  for (int tk = 0; tk < nkv; ++tk) {
    const int kv0 = tk * 64;
    __syncthreads();
    {  // stage K row-major, V transposed
      const u16* ksrc = Kp + (size_t)(kv0 + sr) * 64 + sc4;
      bf16x8 ka = *(const bf16x8*)ksrc;
      bf16x8 kb = *(const bf16x8*)(ksrc + 8);
      *(bf16x8*)&Klds[sr * 72 + sc4] = ka;
      *(bf16x8*)&Klds[sr * 72 + sc4 + 8] = kb;
      const u16* vsrc = Vp + (size_t)(kv0 + sr) * 64 + sc4;
      bf16x8 va = *(const bf16x8*)vsrc;
      bf16x8 vb = *(const bf16x8*)(vsrc + 8);
#pragma unroll
      for (int i = 0; i < 8; ++i) {
        Vt[(sc4 + i) * 72 + sr] = (u16)va[i];
        Vt[(sc4 + 8 + i) * 72 + sr] = (u16)vb[i];
      }
    }
    __syncthreads();

    // S = Q K^T (per wave: 32 q-rows x 64 kv)
    f32x4 sc[2][4];
#pragma unroll
    for (int mr = 0; mr < 2; ++mr)
#pragma unroll
      for (int c = 0; c < 4; ++c) {
        f32x4 z = f32x4{0.f, 0.f, 0.f, 0.f};
#pragma unroll
        for (int kk = 0; kk < 2; ++kk) {
          bf16x8 kf = *(const bf16x8*)&Klds[(c * 16 + l15) * 72 + kk * 32 + lhi * 8];
          z = MFMA(qf[mr][kk], kf, z, 0, 0, 0);
        }
        sc[mr][c] = z;
      }
    // scale + causal mask
#pragma unroll
    for (int mr = 0; mr < 2; ++mr)
#pragma unroll
      for (int c = 0; c < 4; ++c)
#pragma unroll
        for (int i = 0; i < 4; ++i) {
          const int qa = q0w + mr * 16 + lhi * 4 + i;
          const int ka = kv0 + c * 16 + l15;
          const float sv = sc[mr][c][i] * 0.125f;
          sc[mr][c][i] = (ka <= qa) ? sv : -1e30f;
        }
    // online softmax (row lives across the 16 lanes of a quarter-wave)
#pragma unroll
    for (int mr = 0; mr < 2; ++mr)
#pragma unroll
      for (int i = 0; i < 4; ++i) {
        float mx = fmaxf(fmaxf(sc[mr][0][i], sc[mr][1][i]),
                         fmaxf(sc[mr][2][i], sc[mr][3][i]));
#pragma unroll
        for (int off = 1; off < 16; off <<= 1) mx = fmaxf(mx, __shfl_xor(mx, off, 64));
        const float mnew = fmaxf(mrun[mr][i], mx);
        const float rs = __expf(mrun[mr][i] - mnew);
        mrun[mr][i] = mnew;
        float sum = 0.f;
#pragma unroll
        for (int c = 0; c < 4; ++c) {
          const float p = __expf(sc[mr][c][i] - mnew);
          sc[mr][c][i] = p;
          sum += p;
        }
#pragma unroll
        for (int off = 1; off < 16; off <<= 1) sum += __shfl_xor(sum, off, 64);
        lrun[mr][i] = lrun[mr][i] * rs + sum;
#pragma unroll
        for (int dc = 0; dc < 4; ++dc) o[mr][dc][i] *= rs;
      }
    // P -> LDS (bf16), per-wave private region
#pragma unroll
    for (int mr = 0; mr < 2; ++mr)
#pragma unroll
      for (int c = 0; c < 4; ++c)
#pragma unroll
        for (int i = 0; i < 4; ++i)
          Pw[(mr * 16 + lhi * 4 + i) * 72 + c * 16 + l15] = f2bf(sc[mr][c][i]);
    // O += P V
#pragma unroll
    for (int mr = 0; mr < 2; ++mr) {
      bf16x8 pf[2];
#pragma unroll
      for (int kk = 0; kk < 2; ++kk)
        pf[kk] = *(const bf16x8*)&Pw[(mr * 16 + l15) * 72 + kk * 32 + lhi * 8];
#pragma unroll
      for (int dc = 0; dc < 4; ++dc) {
#pragma unroll
        for (int kk = 0; kk < 2; ++kk) {
          bf16x8 vf = *(const bf16x8*)&Vt[(dc * 16 + l15) * 72 + kk * 32 + lhi * 8];
          o[mr][dc] = MFMA(pf[kk], vf, o[mr][dc], 0, 0, 0);
        }
      }
    }
  }

  // epilogue: O/l -> ao [4096][1280] bf16
#pragma unroll
  for (int mr = 0; mr < 2; ++mr)
#pragma unroll
    for (int dc = 0; dc < 4; ++dc)
#pragma unroll
      for (int i = 0; i < 4; ++i) {
        const int qa = q0w + mr * 16 + lhi * 4 + i;
        const float val = o[mr][dc][i] / lrun[mr][i];
        const int d = dc * 16 + l15;
        ao[((size_t)(bb * 2048 + qa)) * 1280 + hh * 64 + d] = f2bf(val);
      }
}

extern "C" void kernel_launch(void* const* d_in, const int* in_sizes, int n_in,
                              void* d_out, int out_size, void* d_ws, size_t ws_size,
                              hipStream_t stream) {
  (void)in_sizes; (void)n_in; (void)out_size; (void)ws_size;
  const float* x      = (const float*)d_in[0];
  const float* w_attn = (const float*)d_in[1];
  const float* b_attn = (const float*)d_in[2];
  const float* w_proj = (const float*)d_in[3];
  const float* b_proj = (const float*)d_in[4];
  float* out = (float*)d_out;

  char* ws = (char*)d_ws;
  u16* x_bf = (u16*)(ws + 0);              // 4096*1280*2  = 10485760 (reused as ao)
  u16* wa_t = (u16*)(ws + 10485760);       // 3840*1280*2  =  9830400
  u16* wp_t = (u16*)(ws + 20316160);       // 1280*1280*2  =  3276800
  u16* q_ws = (u16*)(ws + 23592960);       // 40*2048*64*2 = 10485760
  u16* k_ws = (u16*)(ws + 34078720);
  u16* v_ws = (u16*)(ws + 44564480);       // ends 55050240
  u16* ao   = x_bf;                        // reuse x_bf region after qkv GEMM

  k_cast<<<5120, 256, 0, stream>>>(x, x_bf, 4096 * 1280 / 4);
  k_transpose_cast<<<dim3(60, 20), 256, 0, stream>>>(w_attn, wa_t, 1280, 3840);
  k_transpose_cast<<<dim3(20, 20), 256, 0, stream>>>(w_proj, wp_t, 1280, 1280);
  k_gemm_qkv<<<dim3(32, 30), 256, 0, stream>>>(x_bf, wa_t, b_attn, q_ws, k_ws, v_ws);
  k_attn<<<dim3(16, 40), 256, 0, stream>>>(q_ws, k_ws, v_ws, ao);
  k_gemm_proj<<<dim3(32, 10), 256, 0, stream>>>(ao, wp_t, b_proj, out);
}

// Round 4
// 232.807 us; speedup vs baseline: 1.1282x; 1.1282x over previous
//
#include <hip/hip_runtime.h>

typedef unsigned short u16;
typedef __attribute__((ext_vector_type(8))) short bf16x8;
typedef __attribute__((ext_vector_type(4))) float f32x4;
typedef __attribute__((ext_vector_type(4))) unsigned short u16x4;

#define MFMA16 __builtin_amdgcn_mfma_f32_16x16x32_bf16

__device__ __forceinline__ u16 f2bf(float f) {
  unsigned int u = __float_as_uint(f);
  u += 0x7fff + ((u >> 16) & 1);          // round-to-nearest-even
  return (u16)(u >> 16);
}

__device__ __forceinline__ void gload_lds16(const void* g, void* l) {
  __builtin_amdgcn_global_load_lds((__attribute__((address_space(1))) void*)g,
                                   (__attribute__((address_space(3))) void*)l,
                                   16, 0, 0);
}

// ---------------- cast x (fp32 -> bf16), 4 elems/thread ----------------
__global__ void k_cast(const float* __restrict__ src, u16* __restrict__ dst, int n4) {
  int i = blockIdx.x * 256 + threadIdx.x;
  if (i >= n4) return;
  const float4 v = reinterpret_cast<const float4*>(src)[i];
  u16x4 o = {f2bf(v.x), f2bf(v.y), f2bf(v.z), f2bf(v.w)};
  reinterpret_cast<u16x4*>(dst)[i] = o;
}

// ------- transpose+cast weights: src fp32 [R][C] -> dst bf16 [C][R] -------
__global__ void k_transpose_cast(const float* __restrict__ src, u16* __restrict__ dst,
                                 int R, int C) {
  __shared__ float tile[64][65];
  const int t = threadIdx.x;
  const int c0 = blockIdx.x * 64, r0 = blockIdx.y * 64;
#pragma unroll
  for (int i = 0; i < 16; ++i) {
    int e = i * 256 + t;
    int r = e >> 6, c = e & 63;
    tile[r][c] = src[(size_t)(r0 + r) * C + (c0 + c)];
  }
  __syncthreads();
#pragma unroll
  for (int i = 0; i < 16; ++i) {
    int e = i * 256 + t;
    int r = e >> 6, c = e & 63;
    dst[(size_t)(c0 + r) * R + (r0 + c)] = f2bf(tile[c][r]);
  }
}

// ------- transpose V: [bh][s][64] bf16 -> [bh][64][2048] bf16 -------
__global__ void k_transpose_v(const u16* __restrict__ v, u16* __restrict__ vt) {
  __shared__ unsigned int tile[64][65];
  const int t = threadIdx.x;
  const int sblk = blockIdx.x, bh = blockIdx.y;
  {
    const int sl = t >> 2, d0 = (t & 3) * 16;
    const u16* src = v + ((size_t)(bh * 2048 + sblk * 64 + sl) * 64 + d0);
    bf16x8 a = *(const bf16x8*)src;
    bf16x8 b = *(const bf16x8*)(src + 8);
#pragma unroll
    for (int i = 0; i < 8; ++i) {
      tile[sl][d0 + i] = (u16)a[i];
      tile[sl][d0 + 8 + i] = (u16)b[i];
    }
  }
  __syncthreads();
  {
    const int d = t >> 2, s0 = (t & 3) * 16;
    bf16x8 o0, o1;
#pragma unroll
    for (int i = 0; i < 8; ++i) {
      o0[i] = (short)(u16)tile[s0 + i][d];
      o1[i] = (short)(u16)tile[s0 + 8 + i][d];
    }
    u16* dst = vt + ((size_t)(bh * 64 + d) * 2048 + sblk * 64 + s0);
    *(bf16x8*)dst = o0;
    *(bf16x8*)(dst + 8) = o1;
  }
}

// ---------------- qkv GEMM: [4096,1280] x [3840,1280]^T + bias ----------------
__global__ __launch_bounds__(256, 2) void k_gemm_qkv(
    const u16* __restrict__ A, const u16* __restrict__ Bt,
    const float* __restrict__ bias,
    u16* __restrict__ qo, u16* __restrict__ ko, u16* __restrict__ vo) {
  constexpr int K = 1280;
  __shared__ u16 Alds[128 * 64];
  __shared__ u16 Blds[128 * 64];
  const int t = threadIdx.x;
  const int lane = t & 63, wave = t >> 6;
  const int wr = wave >> 1, wc = wave & 1;
  const int l15 = lane & 15, lhi = lane >> 4;
  const int m0 = blockIdx.x * 128, n0 = blockIdx.y * 128;

  f32x4 acc[4][4];
#pragma unroll
  for (int mi = 0; mi < 4; ++mi)
#pragma unroll
    for (int ni = 0; ni < 4; ++ni) acc[mi][ni] = f32x4{0.f, 0.f, 0.f, 0.f};

  const int srow = t >> 3;
  const int scol = (t & 7) * 8;
  const u16* Ag = A + (size_t)(m0 + srow) * K + scol;
  const u16* Bg = Bt + (size_t)(n0 + srow) * K + scol;
  char* Al = (char*)Alds + wave * 1024;
  char* Bl = (char*)Blds + wave * 1024;

  for (int k0 = 0; k0 < K; k0 += 64) {
    __syncthreads();
#pragma unroll
    for (int it = 0; it < 4; ++it) {
      gload_lds16(Ag + (it * 32) * K + k0, Al + it * 4096);
      gload_lds16(Bg + (it * 32) * K + k0, Bl + it * 4096);
    }
    asm volatile("s_waitcnt vmcnt(0)" ::: "memory");
    __syncthreads();
    const u16* Ab = Alds + (wr * 64 + l15) * 64 + lhi * 8;
    const u16* Bb = Blds + (wc * 64 + l15) * 64 + lhi * 8;
    bf16x8 af[4][2], bfv[4][2];
#pragma unroll
    for (int x = 0; x < 4; ++x) {
      af[x][0] = *(const bf16x8*)(Ab + x * 1024);
      af[x][1] = *(const bf16x8*)(Ab + x * 1024 + 32);
      bfv[x][0] = *(const bf16x8*)(Bb + x * 1024);
      bfv[x][1] = *(const bf16x8*)(Bb + x * 1024 + 32);
    }
#pragma unroll
    for (int mi = 0; mi < 4; ++mi)
#pragma unroll
      for (int ni = 0; ni < 4; ++ni) {
        acc[mi][ni] = MFMA16(af[mi][0], bfv[ni][0], acc[mi][ni], 0, 0, 0);
        acc[mi][ni] = MFMA16(af[mi][1], bfv[ni][1], acc[mi][ni], 0, 0, 0);
      }
  }

  const int which = n0 >= 2560 ? 2 : (n0 >= 1280 ? 1 : 0);
  u16* outp = which == 0 ? qo : (which == 1 ? ko : vo);
#pragma unroll
  for (int ni = 0; ni < 4; ++ni) {
    const int n_abs = n0 + wc * 64 + ni * 16 + l15;
    const int nn = n_abs - which * 1280;
    const int h = nn >> 6, d = nn & 63;
    const float bv = bias[n_abs];
#pragma unroll
    for (int mi = 0; mi < 4; ++mi) {
#pragma unroll
      for (int i = 0; i < 4; ++i) {
        const int m_abs = m0 + wr * 64 + mi * 16 + lhi * 4 + i;
        const int bb = m_abs >> 11, ss = m_abs & 2047;
        outp[(((size_t)(bb * 20 + h) * 2048 + ss) << 6) + d] = f2bf(acc[mi][ni][i] + bv);
      }
    }
  }
}

// ---------------- proj GEMM: [4096,1280] x [1280,1280]^T + bias -> fp32 ----------------
__global__ __launch_bounds__(256, 2) void k_gemm_proj(
    const u16* __restrict__ A, const u16* __restrict__ Bt,
    const float* __restrict__ bias, float* __restrict__ out) {
  constexpr int K = 1280;
  __shared__ u16 Alds[128 * 64];
  __shared__ u16 Blds[128 * 64];
  const int t = threadIdx.x;
  const int lane = t & 63, wave = t >> 6;
  const int wr = wave >> 1, wc = wave & 1;
  const int l15 = lane & 15, lhi = lane >> 4;
  const int m0 = blockIdx.x * 128, n0 = blockIdx.y * 128;

  f32x4 acc[4][4];
#pragma unroll
  for (int mi = 0; mi < 4; ++mi)
#pragma unroll
    for (int ni = 0; ni < 4; ++ni) acc[mi][ni] = f32x4{0.f, 0.f, 0.f, 0.f};

  const int srow = t >> 3;
  const int scol = (t & 7) * 8;
  const u16* Ag = A + (size_t)(m0 + srow) * K + scol;
  const u16* Bg = Bt + (size_t)(n0 + srow) * K + scol;
  char* Al = (char*)Alds + wave * 1024;
  char* Bl = (char*)Blds + wave * 1024;

  for (int k0 = 0; k0 < K; k0 += 64) {
    __syncthreads();
#pragma unroll
    for (int it = 0; it < 4; ++it) {
      gload_lds16(Ag + (it * 32) * K + k0, Al + it * 4096);
      gload_lds16(Bg + (it * 32) * K + k0, Bl + it * 4096);
    }
    asm volatile("s_waitcnt vmcnt(0)" ::: "memory");
    __syncthreads();
    const u16* Ab = Alds + (wr * 64 + l15) * 64 + lhi * 8;
    const u16* Bb = Blds + (wc * 64 + l15) * 64 + lhi * 8;
    bf16x8 af[4][2], bfv[4][2];
#pragma unroll
    for (int x = 0; x < 4; ++x) {
      af[x][0] = *(const bf16x8*)(Ab + x * 1024);
      af[x][1] = *(const bf16x8*)(Ab + x * 1024 + 32);
      bfv[x][0] = *(const bf16x8*)(Bb + x * 1024);
      bfv[x][1] = *(const bf16x8*)(Bb + x * 1024 + 32);
    }
#pragma unroll
    for (int mi = 0; mi < 4; ++mi)
#pragma unroll
      for (int ni = 0; ni < 4; ++ni) {
        acc[mi][ni] = MFMA16(af[mi][0], bfv[ni][0], acc[mi][ni], 0, 0, 0);
        acc[mi][ni] = MFMA16(af[mi][1], bfv[ni][1], acc[mi][ni], 0, 0, 0);
      }
  }

#pragma unroll
  for (int ni = 0; ni < 4; ++ni) {
    const int n_abs = n0 + wc * 64 + ni * 16 + l15;
    const float bv = bias[n_abs];
#pragma unroll
    for (int mi = 0; mi < 4; ++mi) {
#pragma unroll
      for (int i = 0; i < 4; ++i) {
        const int m_abs = m0 + wr * 64 + mi * 16 + lhi * 4 + i;
        out[(size_t)m_abs * 1280 + n_abs] = acc[mi][ni][i] + bv;
      }
    }
  }
}

// ---------------- causal flash attention (round-0 verified structure, barrier-free) ----
// grid (bh=40, qt=16 longest-first). 4 waves x 32 q-rows. KVBLK=64.
// K fragments read directly from K [bh][s][64]; V fragments from pre-transposed
// VT [bh][64][2048]. Only LDS use: per-wave P round-trip (verified in round 0).
__global__ __launch_bounds__(256, 2) void k_attn3(
    const u16* __restrict__ Kq, const u16* __restrict__ Kk,
    const u16* __restrict__ VT, u16* __restrict__ ao) {
  __shared__ u16 Plds[4 * 32 * 72];
  const int t = threadIdx.x;
  const int lane = t & 63, wave = t >> 6;
  const int l15 = lane & 15, lhi = lane >> 4;
  const int bh = blockIdx.x;
  const int qt = 15 - blockIdx.y;          // longest-first
  const int bb = bh / 20, hh = bh % 20;
  const size_t base = (size_t)bh * 2048 * 64;
  const u16* Qp = Kq + base;
  const u16* Kl = Kk + base + (size_t)l15 * 64 + lhi * 8;          // + kv0*64 + c*1024 + kk*32
  const u16* Vl = VT + (size_t)bh * 64 * 2048 + (size_t)l15 * 2048 + lhi * 8;  // + dc*32768 + kv0 + kk*32
  const int q0w = qt * 128 + wave * 32;

  // Q fragments live in registers for the whole kernel
  bf16x8 qf[2][2];
#pragma unroll
  for (int mr = 0; mr < 2; ++mr)
#pragma unroll
    for (int kk = 0; kk < 2; ++kk)
      qf[mr][kk] = *(const bf16x8*)(Qp + (size_t)(q0w + mr * 16 + l15) * 64 + kk * 32 + lhi * 8);

  f32x4 o[2][4];
  float mrun[2][4], lrun[2][4];
#pragma unroll
  for (int mr = 0; mr < 2; ++mr) {
#pragma unroll
    for (int i = 0; i < 4; ++i) { mrun[mr][i] = -1e30f; lrun[mr][i] = 0.f; }
#pragma unroll
    for (int dc = 0; dc < 4; ++dc) o[mr][dc] = f32x4{0.f, 0.f, 0.f, 0.f};
  }

  const int nkv = (qt + 1) * 2;
  u16* Pw = Plds + wave * (32 * 72);

  for (int tk = 0; tk < nkv; ++tk) {
    const int kv0 = tk * 64;
    // S = Q K^T (per wave: 32 q-rows x 64 kv); K fragments direct from global
    f32x4 sc[2][4];
#pragma unroll
    for (int mr = 0; mr < 2; ++mr)
#pragma unroll
      for (int c = 0; c < 4; ++c) {
        f32x4 z = f32x4{0.f, 0.f, 0.f, 0.f};
#pragma unroll
        for (int kk = 0; kk < 2; ++kk) {
          bf16x8 kf = *(const bf16x8*)(Kl + (size_t)kv0 * 64 + c * 1024 + kk * 32);
          z = MFMA16(qf[mr][kk], kf, z, 0, 0, 0);
        }
        sc[mr][c] = z;
      }
    // scale + causal mask
#pragma unroll
    for (int mr = 0; mr < 2; ++mr)
#pragma unroll
      for (int c = 0; c < 4; ++c)
#pragma unroll
        for (int i = 0; i < 4; ++i) {
          const int qa = q0w + mr * 16 + lhi * 4 + i;
          const int ka = kv0 + c * 16 + l15;
          const float sv = sc[mr][c][i] * 0.125f;
          sc[mr][c][i] = (ka <= qa) ? sv : -1e30f;
        }
    // online softmax (row lives across the 16 lanes of a quarter-wave)
#pragma unroll
    for (int mr = 0; mr < 2; ++mr)
#pragma unroll
      for (int i = 0; i < 4; ++i) {
        float mx = fmaxf(fmaxf(sc[mr][0][i], sc[mr][1][i]),
                         fmaxf(sc[mr][2][i], sc[mr][3][i]));
#pragma unroll
        for (int off = 1; off < 16; off <<= 1) mx = fmaxf(mx, __shfl_xor(mx, off, 64));
        const float mnew = fmaxf(mrun[mr][i], mx);
        const float rs = __expf(mrun[mr][i] - mnew);
        mrun[mr][i] = mnew;
        float sum = 0.f;
#pragma unroll
        for (int c = 0; c < 4; ++c) {
          const float p = __expf(sc[mr][c][i] - mnew);
          sc[mr][c][i] = p;
          sum += p;
        }
#pragma unroll
        for (int off = 1; off < 16; off <<= 1) sum += __shfl_xor(sum, off, 64);
        lrun[mr][i] = lrun[mr][i] * rs + sum;
#pragma unroll
        for (int dc = 0; dc < 4; ++dc) o[mr][dc][i] *= rs;
      }
    // P -> LDS (bf16), per-wave private region (no barriers needed)
#pragma unroll
    for (int mr = 0; mr < 2; ++mr)
#pragma unroll
      for (int c = 0; c < 4; ++c)
#pragma unroll
        for (int i = 0; i < 4; ++i)
          Pw[(mr * 16 + lhi * 4 + i) * 72 + c * 16 + l15] = f2bf(sc[mr][c][i]);
    // O += P V ; V fragments direct from global VT
#pragma unroll
    for (int mr = 0; mr < 2; ++mr) {
      bf16x8 pf[2];
#pragma unroll
      for (int kk = 0; kk < 2; ++kk)
        pf[kk] = *(const bf16x8*)&Pw[(mr * 16 + l15) * 72 + kk * 32 + lhi * 8];
#pragma unroll
      for (int dc = 0; dc < 4; ++dc) {
#pragma unroll
        for (int kk = 0; kk < 2; ++kk) {
          bf16x8 vf = *(const bf16x8*)(Vl + dc * 32768 + kv0 + kk * 32);
          o[mr][dc] = MFMA16(pf[kk], vf, o[mr][dc], 0, 0, 0);
        }
      }
    }
  }

  // epilogue: O/l -> ao [b][s][h*64] bf16
#pragma unroll
  for (int mr = 0; mr < 2; ++mr)
#pragma unroll
    for (int dc = 0; dc < 4; ++dc)
#pragma unroll
      for (int i = 0; i < 4; ++i) {
        const int qa = q0w + mr * 16 + lhi * 4 + i;
        const float val = o[mr][dc][i] / lrun[mr][i];
        const int d = dc * 16 + l15;
        ao[((size_t)(bb * 2048 + qa)) * 1280 + hh * 64 + d] = f2bf(val);
      }
}

extern "C" void kernel_launch(void* const* d_in, const int* in_sizes, int n_in,
                              void* d_out, int out_size, void* d_ws, size_t ws_size,
                              hipStream_t stream) {
  (void)in_sizes; (void)n_in; (void)out_size; (void)ws_size;
  const float* x      = (const float*)d_in[0];
  const float* w_attn = (const float*)d_in[1];
  const float* b_attn = (const float*)d_in[2];
  const float* w_proj = (const float*)d_in[3];
  const float* b_proj = (const float*)d_in[4];
  float* out = (float*)d_out;

  char* ws = (char*)d_ws;
  u16* x_bf = (u16*)(ws + 0);              // 10485760 B; reused as vt after gemm_qkv
  u16* wa_t = (u16*)(ws + 10485760);       //  9830400 B
  u16* wp_t = (u16*)(ws + 20316160);       //  3276800 B
  u16* q_ws = (u16*)(ws + 23592960);       // 10485760 B
  u16* k_ws = (u16*)(ws + 34078720);       // 10485760 B
  u16* v_ws = (u16*)(ws + 44564480);       // 10485760 B; reused as ao after transpose_v
  u16* vt   = x_bf;
  u16* ao   = v_ws;

  k_cast<<<5120, 256, 0, stream>>>(x, x_bf, 4096 * 1280 / 4);
  k_transpose_cast<<<dim3(60, 20), 256, 0, stream>>>(w_attn, wa_t, 1280, 3840);
  k_transpose_cast<<<dim3(20, 20), 256, 0, stream>>>(w_proj, wp_t, 1280, 1280);
  k_gemm_qkv<<<dim3(32, 30), 256, 0, stream>>>(x_bf, wa_t, b_attn, q_ws, k_ws, v_ws);
  k_transpose_v<<<dim3(32, 40), 256, 0, stream>>>(v_ws, vt);
  k_attn3<<<dim3(40, 16), 256, 0, stream>>>(q_ws, k_ws, vt, ao);
  k_gemm_proj<<<dim3(32, 10), 256, 0, stream>>>(ao, wp_t, b_proj, out);
}

// Round 5
// 205.942 us; speedup vs baseline: 1.2754x; 1.1304x over previous
//
#include <hip/hip_runtime.h>

typedef unsigned short u16;
typedef __attribute__((ext_vector_type(8))) short bf16x8;
typedef __attribute__((ext_vector_type(4))) float f32x4;
typedef __attribute__((ext_vector_type(4))) unsigned short u16x4;

#define MFMA16 __builtin_amdgcn_mfma_f32_16x16x32_bf16

__device__ __forceinline__ u16 f2bf(float f) {
  unsigned int u = __float_as_uint(f);
  u += 0x7fff + ((u >> 16) & 1);          // round-to-nearest-even
  return (u16)(u >> 16);
}

__device__ __forceinline__ float vexp2(float x) {
  float r; asm("v_exp_f32 %0, %1" : "=v"(r) : "v"(x)); return r;
}

// DPP lane-permute within 16-lane rows (VALU-latency, replaces ds_bpermute shuffles)
template<int CTRL>
__device__ __forceinline__ float dppf(float v) {
  return __int_as_float(__builtin_amdgcn_update_dpp(0, __float_as_int(v), CTRL, 0xF, 0xF, true));
}
__device__ __forceinline__ float rowmax16(float v) {
  v = fmaxf(v, dppf<0xB1>(v));   // quad_perm [1,0,3,2]  (xor 1)
  v = fmaxf(v, dppf<0x4E>(v));   // quad_perm [2,3,0,1]  (xor 2)
  v = fmaxf(v, dppf<0x141>(v));  // row_half_mirror      (covers xor 4)
  v = fmaxf(v, dppf<0x140>(v));  // row_mirror           (covers xor 8)
  return v;
}
__device__ __forceinline__ float rowsum16(float v) {
  v += dppf<0xB1>(v);
  v += dppf<0x4E>(v);
  v += dppf<0x141>(v);
  v += dppf<0x140>(v);
  return v;
}

__device__ __forceinline__ void gload_lds16(const void* g, void* l) {
  __builtin_amdgcn_global_load_lds((__attribute__((address_space(1))) void*)g,
                                   (__attribute__((address_space(3))) void*)l,
                                   16, 0, 0);
}

// ---------------- cast x (fp32 -> bf16), 4 elems/thread ----------------
__global__ void k_cast(const float* __restrict__ src, u16* __restrict__ dst, int n4) {
  int i = blockIdx.x * 256 + threadIdx.x;
  if (i >= n4) return;
  const float4 v = reinterpret_cast<const float4*>(src)[i];
  u16x4 o = {f2bf(v.x), f2bf(v.y), f2bf(v.z), f2bf(v.w)};
  reinterpret_cast<u16x4*>(dst)[i] = o;
}

// ------- transpose+cast weights: src fp32 [R][C] -> dst bf16 [C][R] -------
__global__ void k_transpose_cast(const float* __restrict__ src, u16* __restrict__ dst,
                                 int R, int C) {
  __shared__ float tile[64][65];
  const int t = threadIdx.x;
  const int c0 = blockIdx.x * 64, r0 = blockIdx.y * 64;
#pragma unroll
  for (int i = 0; i < 16; ++i) {
    int e = i * 256 + t;
    int r = e >> 6, c = e & 63;
    tile[r][c] = src[(size_t)(r0 + r) * C + (c0 + c)];
  }
  __syncthreads();
#pragma unroll
  for (int i = 0; i < 16; ++i) {
    int e = i * 256 + t;
    int r = e >> 6, c = e & 63;
    dst[(size_t)(c0 + r) * R + (r0 + c)] = f2bf(tile[c][r]);
  }
}

// ------- transpose V: [bh][s][64] bf16 -> [bh][64][2048] bf16 -------
__global__ void k_transpose_v(const u16* __restrict__ v, u16* __restrict__ vt) {
  __shared__ unsigned int tile[64][65];
  const int t = threadIdx.x;
  const int sblk = blockIdx.x, bh = blockIdx.y;
  {
    const int sl = t >> 2, d0 = (t & 3) * 16;
    const u16* src = v + ((size_t)(bh * 2048 + sblk * 64 + sl) * 64 + d0);
    bf16x8 a = *(const bf16x8*)src;
    bf16x8 b = *(const bf16x8*)(src + 8);
#pragma unroll
    for (int i = 0; i < 8; ++i) {
      tile[sl][d0 + i] = (u16)a[i];
      tile[sl][d0 + 8 + i] = (u16)b[i];
    }
  }
  __syncthreads();
  {
    const int d = t >> 2, s0 = (t & 3) * 16;
    bf16x8 o0, o1;
#pragma unroll
    for (int i = 0; i < 8; ++i) {
      o0[i] = (short)(u16)tile[s0 + i][d];
      o1[i] = (short)(u16)tile[s0 + 8 + i][d];
    }
    u16* dst = vt + ((size_t)(bh * 64 + d) * 2048 + sblk * 64 + s0);
    *(bf16x8*)dst = o0;
    *(bf16x8*)(dst + 8) = o1;
  }
}

// ---------------- qkv GEMM: [4096,1280] x [3840,1280]^T + bias ----------------
__global__ __launch_bounds__(256, 2) void k_gemm_qkv(
    const u16* __restrict__ A, const u16* __restrict__ Bt,
    const float* __restrict__ bias,
    u16* __restrict__ qo, u16* __restrict__ ko, u16* __restrict__ vo) {
  constexpr int K = 1280;
  __shared__ u16 Alds[128 * 64];
  __shared__ u16 Blds[128 * 64];
  const int t = threadIdx.x;
  const int lane = t & 63, wave = t >> 6;
  const int wr = wave >> 1, wc = wave & 1;
  const int l15 = lane & 15, lhi = lane >> 4;
  const int m0 = blockIdx.x * 128, n0 = blockIdx.y * 128;

  f32x4 acc[4][4];
#pragma unroll
  for (int mi = 0; mi < 4; ++mi)
#pragma unroll
    for (int ni = 0; ni < 4; ++ni) acc[mi][ni] = f32x4{0.f, 0.f, 0.f, 0.f};

  const int srow = t >> 3;
  const int scol = (t & 7) * 8;
  const u16* Ag = A + (size_t)(m0 + srow) * K + scol;
  const u16* Bg = Bt + (size_t)(n0 + srow) * K + scol;
  char* Al = (char*)Alds + wave * 1024;
  char* Bl = (char*)Blds + wave * 1024;

  for (int k0 = 0; k0 < K; k0 += 64) {
    __syncthreads();
#pragma unroll
    for (int it = 0; it < 4; ++it) {
      gload_lds16(Ag + (it * 32) * K + k0, Al + it * 4096);
      gload_lds16(Bg + (it * 32) * K + k0, Bl + it * 4096);
    }
    asm volatile("s_waitcnt vmcnt(0)" ::: "memory");
    __syncthreads();
    const u16* Ab = Alds + (wr * 64 + l15) * 64 + lhi * 8;
    const u16* Bb = Blds + (wc * 64 + l15) * 64 + lhi * 8;
    bf16x8 af[4][2], bfv[4][2];
#pragma unroll
    for (int x = 0; x < 4; ++x) {
      af[x][0] = *(const bf16x8*)(Ab + x * 1024);
      af[x][1] = *(const bf16x8*)(Ab + x * 1024 + 32);
      bfv[x][0] = *(const bf16x8*)(Bb + x * 1024);
      bfv[x][1] = *(const bf16x8*)(Bb + x * 1024 + 32);
    }
#pragma unroll
    for (int mi = 0; mi < 4; ++mi)
#pragma unroll
      for (int ni = 0; ni < 4; ++ni) {
        acc[mi][ni] = MFMA16(af[mi][0], bfv[ni][0], acc[mi][ni], 0, 0, 0);
        acc[mi][ni] = MFMA16(af[mi][1], bfv[ni][1], acc[mi][ni], 0, 0, 0);
      }
  }

  const int which = n0 >= 2560 ? 2 : (n0 >= 1280 ? 1 : 0);
  u16* outp = which == 0 ? qo : (which == 1 ? ko : vo);
#pragma unroll
  for (int ni = 0; ni < 4; ++ni) {
    const int n_abs = n0 + wc * 64 + ni * 16 + l15;
    const int nn = n_abs - which * 1280;
    const int h = nn >> 6, d = nn & 63;
    const float bv = bias[n_abs];
#pragma unroll
    for (int mi = 0; mi < 4; ++mi) {
#pragma unroll
      for (int i = 0; i < 4; ++i) {
        const int m_abs = m0 + wr * 64 + mi * 16 + lhi * 4 + i;
        const int bb = m_abs >> 11, ss = m_abs & 2047;
        outp[(((size_t)(bb * 20 + h) * 2048 + ss) << 6) + d] = f2bf(acc[mi][ni][i] + bv);
      }
    }
  }
}

// ---------------- proj GEMM: [4096,1280] x [1280,1280]^T + bias -> fp32 ----------------
__global__ __launch_bounds__(256, 2) void k_gemm_proj(
    const u16* __restrict__ A, const u16* __restrict__ Bt,
    const float* __restrict__ bias, float* __restrict__ out) {
  constexpr int K = 1280;
  __shared__ u16 Alds[128 * 64];
  __shared__ u16 Blds[128 * 64];
  const int t = threadIdx.x;
  const int lane = t & 63, wave = t >> 6;
  const int wr = wave >> 1, wc = wave & 1;
  const int l15 = lane & 15, lhi = lane >> 4;
  const int m0 = blockIdx.x * 128, n0 = blockIdx.y * 128;

  f32x4 acc[4][4];
#pragma unroll
  for (int mi = 0; mi < 4; ++mi)
#pragma unroll
    for (int ni = 0; ni < 4; ++ni) acc[mi][ni] = f32x4{0.f, 0.f, 0.f, 0.f};

  const int srow = t >> 3;
  const int scol = (t & 7) * 8;
  const u16* Ag = A + (size_t)(m0 + srow) * K + scol;
  const u16* Bg = Bt + (size_t)(n0 + srow) * K + scol;
  char* Al = (char*)Alds + wave * 1024;
  char* Bl = (char*)Blds + wave * 1024;

  for (int k0 = 0; k0 < K; k0 += 64) {
    __syncthreads();
#pragma unroll
    for (int it = 0; it < 4; ++it) {
      gload_lds16(Ag + (it * 32) * K + k0, Al + it * 4096);
      gload_lds16(Bg + (it * 32) * K + k0, Bl + it * 4096);
    }
    asm volatile("s_waitcnt vmcnt(0)" ::: "memory");
    __syncthreads();
    const u16* Ab = Alds + (wr * 64 + l15) * 64 + lhi * 8;
    const u16* Bb = Blds + (wc * 64 + l15) * 64 + lhi * 8;
    bf16x8 af[4][2], bfv[4][2];
#pragma unroll
    for (int x = 0; x < 4; ++x) {
      af[x][0] = *(const bf16x8*)(Ab + x * 1024);
      af[x][1] = *(const bf16x8*)(Ab + x * 1024 + 32);
      bfv[x][0] = *(const bf16x8*)(Bb + x * 1024);
      bfv[x][1] = *(const bf16x8*)(Bb + x * 1024 + 32);
    }
#pragma unroll
    for (int mi = 0; mi < 4; ++mi)
#pragma unroll
      for (int ni = 0; ni < 4; ++ni) {
        acc[mi][ni] = MFMA16(af[mi][0], bfv[ni][0], acc[mi][ni], 0, 0, 0);
        acc[mi][ni] = MFMA16(af[mi][1], bfv[ni][1], acc[mi][ni], 0, 0, 0);
      }
  }

#pragma unroll
  for (int ni = 0; ni < 4; ++ni) {
    const int n_abs = n0 + wc * 64 + ni * 16 + l15;
    const float bv = bias[n_abs];
#pragma unroll
    for (int mi = 0; mi < 4; ++mi) {
#pragma unroll
      for (int i = 0; i < 4; ++i) {
        const int m_abs = m0 + wr * 64 + mi * 16 + lhi * 4 + i;
        out[(size_t)m_abs * 1280 + n_abs] = acc[mi][ni][i] + bv;
      }
    }
  }
}

// ---------------- causal flash attention v4: DPP softmax, deferred sum, 1-wave blocks ----
// grid (bh=40, 64 q-tiles longest-first), 64 threads = 1 wave, 32 q-rows/wave, KVBLK=64.
// Verified round-0/4 MFMA16 fragment model. K direct from [bh][s][64]; V from VT
// [bh][64][2048]. LDS: per-block P round-trip only. All reductions via DPP (VALU speed).
__global__ __launch_bounds__(64, 3) void k_attn4(
    const u16* __restrict__ Qg, const u16* __restrict__ Kg,
    const u16* __restrict__ VT, u16* __restrict__ ao) {
  __shared__ u16 Plds[32 * 72];
  const int lane = threadIdx.x;
  const int l15 = lane & 15, lhi = lane >> 4;
  const int bh = blockIdx.x;
  const int qt = 63 - blockIdx.y;          // longest-first
  const int bb = bh / 20, hh = bh % 20;
  const int q0 = qt * 32;
  const int nkv = (qt >> 1) + 1;           // KV tiles of 64 covering [0, q0+32)
  const size_t base = (size_t)bh * 2048 * 64;
  const u16* Kl = Kg + base + (size_t)l15 * 64 + lhi * 8;          // + kv0*64 + c*1024 + kk*32
  const u16* Vl = VT + (size_t)bh * 64 * 2048 + (size_t)l15 * 2048 + lhi * 8;  // + dc*32768 + kv0 + kk*32

  // Q fragments in registers for the whole kernel
  bf16x8 qf[2][2];
#pragma unroll
  for (int mr = 0; mr < 2; ++mr)
#pragma unroll
    for (int kk = 0; kk < 2; ++kk)
      qf[mr][kk] = *(const bf16x8*)(Qg + base + (size_t)(q0 + mr * 16 + l15) * 64 + kk * 32 + lhi * 8);

  f32x4 o[2][4];
  float m2[2][4], lp[2][4];                // m in exp2-scaled domain; lp = per-lane partial sum
#pragma unroll
  for (int mr = 0; mr < 2; ++mr) {
#pragma unroll
    for (int i = 0; i < 4; ++i) { m2[mr][i] = -3.0e38f; lp[mr][i] = 0.f; }
#pragma unroll
    for (int dc = 0; dc < 4; ++dc) o[mr][dc] = f32x4{0.f, 0.f, 0.f, 0.f};
  }
  const float c1 = 0.18033688f;            // 0.125 * log2(e)

  for (int tk = 0; tk < nkv; ++tk) {
    const int kv0 = tk * 64;
    // ---- S = Q K^T (32 q-rows x 64 kv), K fragments direct from global ----
    f32x4 sc[2][4];
#pragma unroll
    for (int mr = 0; mr < 2; ++mr)
#pragma unroll
      for (int c = 0; c < 4; ++c) {
        f32x4 z = f32x4{0.f, 0.f, 0.f, 0.f};
#pragma unroll
        for (int kk = 0; kk < 2; ++kk) {
          bf16x8 kf = *(const bf16x8*)(Kl + (size_t)kv0 * 64 + c * 1024 + kk * 32);
          z = MFMA16(qf[mr][kk], kf, z, 0, 0, 0);
        }
        sc[mr][c] = z;
      }
    // ---- causal mask: provably only the last tile intersects the diagonal ----
    if (tk == nkv - 1) {
#pragma unroll
      for (int mr = 0; mr < 2; ++mr)
#pragma unroll
        for (int c = 0; c < 4; ++c)
#pragma unroll
          for (int i = 0; i < 4; ++i) {
            const int qa = q0 + mr * 16 + lhi * 4 + i;
            const int ka = kv0 + c * 16 + l15;
            sc[mr][c][i] = (ka <= qa) ? sc[mr][c][i] : -3.0e38f;
          }
    }
    // ---- tile row-max (in-lane over c, then 4 DPP steps across 16 lanes) ----
    float tm[2][4];
    bool need = false;
#pragma unroll
    for (int mr = 0; mr < 2; ++mr)
#pragma unroll
      for (int i = 0; i < 4; ++i) {
        float mx = fmaxf(fmaxf(sc[mr][0][i], sc[mr][1][i]),
                         fmaxf(sc[mr][2][i], sc[mr][3][i]));
        mx = rowmax16(mx) * c1;            // scaled (exp2) domain
        tm[mr][i] = mx;
        need |= (mx > m2[mr][i] + 11.5f);  // THR ~ e^8 equivalent
      }
    // ---- deferred rescale (wave-uniform branch) ----
    if (__any(need)) {
#pragma unroll
      for (int mr = 0; mr < 2; ++mr)
#pragma unroll
        for (int i = 0; i < 4; ++i) {
          const float mn = fmaxf(m2[mr][i], tm[mr][i]);
          const float rs = vexp2(m2[mr][i] - mn);
          m2[mr][i] = mn;
          lp[mr][i] *= rs;
#pragma unroll
          for (int dc = 0; dc < 4; ++dc) o[mr][dc][i] *= rs;
        }
    }
    // ---- p = exp2(s*c1 - m2); per-lane partial sums; P -> LDS ----
#pragma unroll
    for (int mr = 0; mr < 2; ++mr)
#pragma unroll
      for (int i = 0; i < 4; ++i) {
        float psum = 0.f;
#pragma unroll
        for (int c = 0; c < 4; ++c) {
          const float p = vexp2(__builtin_fmaf(sc[mr][c][i], c1, -m2[mr][i]));
          psum += p;
          Plds[(mr * 16 + lhi * 4 + i) * 72 + c * 16 + l15] = f2bf(p);
        }
        lp[mr][i] += psum;
      }
    // ---- O += P V ; V fragments direct from global VT ----
#pragma unroll
    for (int mr = 0; mr < 2; ++mr) {
      bf16x8 pf[2];
#pragma unroll
      for (int kk = 0; kk < 2; ++kk)
        pf[kk] = *(const bf16x8*)&Plds[(mr * 16 + l15) * 72 + kk * 32 + lhi * 8];
#pragma unroll
      for (int dc = 0; dc < 4; ++dc) {
#pragma unroll
        for (int kk = 0; kk < 2; ++kk) {
          bf16x8 vf = *(const bf16x8*)(Vl + dc * 32768 + kv0 + kk * 32);
          o[mr][dc] = MFMA16(pf[kk], vf, o[mr][dc], 0, 0, 0);
        }
      }
    }
  }

  // ---- epilogue: complete l across lanes (DPP), divide, store ----
#pragma unroll
  for (int mr = 0; mr < 2; ++mr)
#pragma unroll
    for (int i = 0; i < 4; ++i) {
      const float lfull = rowsum16(lp[mr][i]);
      const float inv = 1.0f / lfull;
      const int qa = q0 + mr * 16 + lhi * 4 + i;
#pragma unroll
      for (int dc = 0; dc < 4; ++dc) {
        const int d = dc * 16 + l15;
        ao[((size_t)(bb * 2048 + qa)) * 1280 + hh * 64 + d] = f2bf(o[mr][dc][i] * inv);
      }
    }
}

extern "C" void kernel_launch(void* const* d_in, const int* in_sizes, int n_in,
                              void* d_out, int out_size, void* d_ws, size_t ws_size,
                              hipStream_t stream) {
  (void)in_sizes; (void)n_in; (void)out_size; (void)ws_size;
  const float* x      = (const float*)d_in[0];
  const float* w_attn = (const float*)d_in[1];
  const float* b_attn = (const float*)d_in[2];
  const float* w_proj = (const float*)d_in[3];
  const float* b_proj = (const float*)d_in[4];
  float* out = (float*)d_out;

  char* ws = (char*)d_ws;
  u16* x_bf = (u16*)(ws + 0);              // 10485760 B; reused as vt after gemm_qkv
  u16* wa_t = (u16*)(ws + 10485760);       //  9830400 B
  u16* wp_t = (u16*)(ws + 20316160);       //  3276800 B
  u16* q_ws = (u16*)(ws + 23592960);       // 10485760 B
  u16* k_ws = (u16*)(ws + 34078720);       // 10485760 B
  u16* v_ws = (u16*)(ws + 44564480);       // 10485760 B; reused as ao after transpose_v
  u16* vt   = x_bf;
  u16* ao   = v_ws;

  k_cast<<<5120, 256, 0, stream>>>(x, x_bf, 4096 * 1280 / 4);
  k_transpose_cast<<<dim3(60, 20), 256, 0, stream>>>(w_attn, wa_t, 1280, 3840);
  k_transpose_cast<<<dim3(20, 20), 256, 0, stream>>>(w_proj, wp_t, 1280, 1280);
  k_gemm_qkv<<<dim3(32, 30), 256, 0, stream>>>(x_bf, wa_t, b_attn, q_ws, k_ws, v_ws);
  k_transpose_v<<<dim3(32, 40), 256, 0, stream>>>(v_ws, vt);
  k_attn4<<<dim3(40, 64), 64, 0, stream>>>(q_ws, k_ws, vt, ao);
  k_gemm_proj<<<dim3(32, 10), 256, 0, stream>>>(ao, wp_t, b_proj, out);
}

// Round 6
// 191.971 us; speedup vs baseline: 1.3682x; 1.0728x over previous
//
#include <hip/hip_runtime.h>

typedef unsigned short u16;
typedef __attribute__((ext_vector_type(8))) short bf16x8;
typedef __attribute__((ext_vector_type(4))) float f32x4;
typedef __attribute__((ext_vector_type(4))) unsigned short u16x4;

#define MFMA16 __builtin_amdgcn_mfma_f32_16x16x32_bf16

__device__ __forceinline__ u16 f2bf(float f) {
  unsigned int u = __float_as_uint(f);
  u += 0x7fff + ((u >> 16) & 1);          // round-to-nearest-even
  return (u16)(u >> 16);
}

__device__ __forceinline__ float vexp2(float x) {
  float r; asm("v_exp_f32 %0, %1" : "=v"(r) : "v"(x)); return r;
}

// DPP lane-permute within 16-lane rows (VALU-latency, replaces ds_bpermute shuffles)
template<int CTRL>
__device__ __forceinline__ float dppf(float v) {
  return __int_as_float(__builtin_amdgcn_update_dpp(0, __float_as_int(v), CTRL, 0xF, 0xF, true));
}
__device__ __forceinline__ float rowmax16(float v) {
  v = fmaxf(v, dppf<0xB1>(v));   // quad_perm [1,0,3,2]  (xor 1)
  v = fmaxf(v, dppf<0x4E>(v));   // quad_perm [2,3,0,1]  (xor 2)
  v = fmaxf(v, dppf<0x141>(v));  // row_half_mirror      (covers xor 4)
  v = fmaxf(v, dppf<0x140>(v));  // row_mirror           (covers xor 8)
  return v;
}
__device__ __forceinline__ float rowsum16(float v) {
  v += dppf<0xB1>(v);
  v += dppf<0x4E>(v);
  v += dppf<0x141>(v);
  v += dppf<0x140>(v);
  return v;
}

__device__ __forceinline__ void gload_lds16(const void* g, void* l) {
  __builtin_amdgcn_global_load_lds((__attribute__((address_space(1))) void*)g,
                                   (__attribute__((address_space(3))) void*)l,
                                   16, 0, 0);
}

// ---------------- cast x (fp32 -> bf16), 4 elems/thread ----------------
__global__ void k_cast(const float* __restrict__ src, u16* __restrict__ dst, int n4) {
  int i = blockIdx.x * 256 + threadIdx.x;
  if (i >= n4) return;
  const float4 v = reinterpret_cast<const float4*>(src)[i];
  u16x4 o = {f2bf(v.x), f2bf(v.y), f2bf(v.z), f2bf(v.w)};
  reinterpret_cast<u16x4*>(dst)[i] = o;
}

// ------- transpose+cast weights: src fp32 [R][C] -> dst bf16 [C][R] -------
__global__ void k_transpose_cast(const float* __restrict__ src, u16* __restrict__ dst,
                                 int R, int C) {
  __shared__ float tile[64][65];
  const int t = threadIdx.x;
  const int c0 = blockIdx.x * 64, r0 = blockIdx.y * 64;
#pragma unroll
  for (int i = 0; i < 16; ++i) {
    int e = i * 256 + t;
    int r = e >> 6, c = e & 63;
    tile[r][c] = src[(size_t)(r0 + r) * C + (c0 + c)];
  }
  __syncthreads();
#pragma unroll
  for (int i = 0; i < 16; ++i) {
    int e = i * 256 + t;
    int r = e >> 6, c = e & 63;
    dst[(size_t)(c0 + r) * R + (r0 + c)] = f2bf(tile[c][r]);
  }
}

// ------- transpose V: [bh][s][64] bf16 -> [bh][64][2048] bf16 -------
__global__ void k_transpose_v(const u16* __restrict__ v, u16* __restrict__ vt) {
  __shared__ unsigned int tile[64][65];
  const int t = threadIdx.x;
  const int sblk = blockIdx.x, bh = blockIdx.y;
  {
    const int sl = t >> 2, d0 = (t & 3) * 16;
    const u16* src = v + ((size_t)(bh * 2048 + sblk * 64 + sl) * 64 + d0);
    bf16x8 a = *(const bf16x8*)src;
    bf16x8 b = *(const bf16x8*)(src + 8);
#pragma unroll
    for (int i = 0; i < 8; ++i) {
      tile[sl][d0 + i] = (u16)a[i];
      tile[sl][d0 + 8 + i] = (u16)b[i];
    }
  }
  __syncthreads();
  {
    const int d = t >> 2, s0 = (t & 3) * 16;
    bf16x8 o0, o1;
#pragma unroll
    for (int i = 0; i < 8; ++i) {
      o0[i] = (short)(u16)tile[s0 + i][d];
      o1[i] = (short)(u16)tile[s0 + 8 + i][d];
    }
    u16* dst = vt + ((size_t)(bh * 64 + d) * 2048 + sblk * 64 + s0);
    *(bf16x8*)dst = o0;
    *(bf16x8*)(dst + 8) = o1;
  }
}

// ---------------- qkv GEMM: [4096,1280] x [3840,1280]^T + bias ----------------
__global__ __launch_bounds__(256, 2) void k_gemm_qkv(
    const u16* __restrict__ A, const u16* __restrict__ Bt,
    const float* __restrict__ bias,
    u16* __restrict__ qo, u16* __restrict__ ko, u16* __restrict__ vo) {
  constexpr int K = 1280;
  __shared__ u16 Alds[128 * 64];
  __shared__ u16 Blds[128 * 64];
  const int t = threadIdx.x;
  const int lane = t & 63, wave = t >> 6;
  const int wr = wave >> 1, wc = wave & 1;
  const int l15 = lane & 15, lhi = lane >> 4;
  const int m0 = blockIdx.x * 128, n0 = blockIdx.y * 128;

  f32x4 acc[4][4];
#pragma unroll
  for (int mi = 0; mi < 4; ++mi)
#pragma unroll
    for (int ni = 0; ni < 4; ++ni) acc[mi][ni] = f32x4{0.f, 0.f, 0.f, 0.f};

  const int srow = t >> 3;
  const int scol = (t & 7) * 8;
  const u16* Ag = A + (size_t)(m0 + srow) * K + scol;
  const u16* Bg = Bt + (size_t)(n0 + srow) * K + scol;
  char* Al = (char*)Alds + wave * 1024;
  char* Bl = (char*)Blds + wave * 1024;

  for (int k0 = 0; k0 < K; k0 += 64) {
    __syncthreads();
#pragma unroll
    for (int it = 0; it < 4; ++it) {
      gload_lds16(Ag + (it * 32) * K + k0, Al + it * 4096);
      gload_lds16(Bg + (it * 32) * K + k0, Bl + it * 4096);
    }
    asm volatile("s_waitcnt vmcnt(0)" ::: "memory");
    __syncthreads();
    const u16* Ab = Alds + (wr * 64 + l15) * 64 + lhi * 8;
    const u16* Bb = Blds + (wc * 64 + l15) * 64 + lhi * 8;
    bf16x8 af[4][2], bfv[4][2];
#pragma unroll
    for (int x = 0; x < 4; ++x) {
      af[x][0] = *(const bf16x8*)(Ab + x * 1024);
      af[x][1] = *(const bf16x8*)(Ab + x * 1024 + 32);
      bfv[x][0] = *(const bf16x8*)(Bb + x * 1024);
      bfv[x][1] = *(const bf16x8*)(Bb + x * 1024 + 32);
    }
#pragma unroll
    for (int mi = 0; mi < 4; ++mi)
#pragma unroll
      for (int ni = 0; ni < 4; ++ni) {
        acc[mi][ni] = MFMA16(af[mi][0], bfv[ni][0], acc[mi][ni], 0, 0, 0);
        acc[mi][ni] = MFMA16(af[mi][1], bfv[ni][1], acc[mi][ni], 0, 0, 0);
      }
  }

  const int which = n0 >= 2560 ? 2 : (n0 >= 1280 ? 1 : 0);
  u16* outp = which == 0 ? qo : (which == 1 ? ko : vo);
#pragma unroll
  for (int ni = 0; ni < 4; ++ni) {
    const int n_abs = n0 + wc * 64 + ni * 16 + l15;
    const int nn = n_abs - which * 1280;
    const int h = nn >> 6, d = nn & 63;
    const float bv = bias[n_abs];
#pragma unroll
    for (int mi = 0; mi < 4; ++mi) {
#pragma unroll
      for (int i = 0; i < 4; ++i) {
        const int m_abs = m0 + wr * 64 + mi * 16 + lhi * 4 + i;
        const int bb = m_abs >> 11, ss = m_abs & 2047;
        outp[(((size_t)(bb * 20 + h) * 2048 + ss) << 6) + d] = f2bf(acc[mi][ni][i] + bv);
      }
    }
  }
}

// ---------------- proj GEMM: [4096,1280] x [1280,1280]^T + bias -> fp32 ----------------
__global__ __launch_bounds__(256, 2) void k_gemm_proj(
    const u16* __restrict__ A, const u16* __restrict__ Bt,
    const float* __restrict__ bias, float* __restrict__ out) {
  constexpr int K = 1280;
  __shared__ u16 Alds[128 * 64];
  __shared__ u16 Blds[128 * 64];
  const int t = threadIdx.x;
  const int lane = t & 63, wave = t >> 6;
  const int wr = wave >> 1, wc = wave & 1;
  const int l15 = lane & 15, lhi = lane >> 4;
  const int m0 = blockIdx.x * 128, n0 = blockIdx.y * 128;

  f32x4 acc[4][4];
#pragma unroll
  for (int mi = 0; mi < 4; ++mi)
#pragma unroll
    for (int ni = 0; ni < 4; ++ni) acc[mi][ni] = f32x4{0.f, 0.f, 0.f, 0.f};

  const int srow = t >> 3;
  const int scol = (t & 7) * 8;
  const u16* Ag = A + (size_t)(m0 + srow) * K + scol;
  const u16* Bg = Bt + (size_t)(n0 + srow) * K + scol;
  char* Al = (char*)Alds + wave * 1024;
  char* Bl = (char*)Blds + wave * 1024;

  for (int k0 = 0; k0 < K; k0 += 64) {
    __syncthreads();
#pragma unroll
    for (int it = 0; it < 4; ++it) {
      gload_lds16(Ag + (it * 32) * K + k0, Al + it * 4096);
      gload_lds16(Bg + (it * 32) * K + k0, Bl + it * 4096);
    }
    asm volatile("s_waitcnt vmcnt(0)" ::: "memory");
    __syncthreads();
    const u16* Ab = Alds + (wr * 64 + l15) * 64 + lhi * 8;
    const u16* Bb = Blds + (wc * 64 + l15) * 64 + lhi * 8;
    bf16x8 af[4][2], bfv[4][2];
#pragma unroll
    for (int x = 0; x < 4; ++x) {
      af[x][0] = *(const bf16x8*)(Ab + x * 1024);
      af[x][1] = *(const bf16x8*)(Ab + x * 1024 + 32);
      bfv[x][0] = *(const bf16x8*)(Bb + x * 1024);
      bfv[x][1] = *(const bf16x8*)(Bb + x * 1024 + 32);
    }
#pragma unroll
    for (int mi = 0; mi < 4; ++mi)
#pragma unroll
      for (int ni = 0; ni < 4; ++ni) {
        acc[mi][ni] = MFMA16(af[mi][0], bfv[ni][0], acc[mi][ni], 0, 0, 0);
        acc[mi][ni] = MFMA16(af[mi][1], bfv[ni][1], acc[mi][ni], 0, 0, 0);
      }
  }

#pragma unroll
  for (int ni = 0; ni < 4; ++ni) {
    const int n_abs = n0 + wc * 64 + ni * 16 + l15;
    const float bv = bias[n_abs];
#pragma unroll
    for (int mi = 0; mi < 4; ++mi) {
#pragma unroll
      for (int i = 0; i < 4; ++i) {
        const int m_abs = m0 + wr * 64 + mi * 16 + lhi * 4 + i;
        out[(size_t)m_abs * 1280 + n_abs] = acc[mi][ni][i] + bv;
      }
    }
  }
}

// ---------------- causal flash attention v5: issue-early K/V refill (T14) ----
// grid (bh=40, 64 q-tiles longest-first), 64 threads = 1 wave, 32 q-rows/wave, KVBLK=64.
// Same verified arithmetic as v4. K/V fragments for tile t+1 are loaded into the
// registers IMMEDIATELY after tile t's MFMAs consume them, so the ~200-400cyc L2
// latency hides under softmax/PV of the current tile instead of stalling each tile.
__global__ __launch_bounds__(64, 2) void k_attn5(
    const u16* __restrict__ Qg, const u16* __restrict__ Kg,
    const u16* __restrict__ VT, u16* __restrict__ ao) {
  __shared__ u16 Plds[32 * 72];
  const int lane = threadIdx.x;
  const int l15 = lane & 15, lhi = lane >> 4;
  const int bh = blockIdx.x;
  const int qt = 63 - blockIdx.y;          // longest-first
  const int bb = bh / 20, hh = bh % 20;
  const int q0 = qt * 32;
  const int nkv = (qt >> 1) + 1;           // KV tiles of 64 covering [0, q0+32)
  const size_t base = (size_t)bh * 2048 * 64;
  const u16* Kl = Kg + base + (size_t)l15 * 64 + lhi * 8;          // + kv0*64 + c*1024 + kk*32
  const u16* Vl = VT + (size_t)bh * 64 * 2048 + (size_t)l15 * 2048 + lhi * 8;  // + dc*32768 + kv0 + kk*32

  // Q fragments in registers for the whole kernel
  bf16x8 qf[2][2];
#pragma unroll
  for (int mr = 0; mr < 2; ++mr)
#pragma unroll
    for (int kk = 0; kk < 2; ++kk)
      qf[mr][kk] = *(const bf16x8*)(Qg + base + (size_t)(q0 + mr * 16 + l15) * 64 + kk * 32 + lhi * 8);

  f32x4 o[2][4];
  float m2[2][4], lp[2][4];                // m in exp2-scaled domain; lp = per-lane partial sum
#pragma unroll
  for (int mr = 0; mr < 2; ++mr) {
#pragma unroll
    for (int i = 0; i < 4; ++i) { m2[mr][i] = -3.0e38f; lp[mr][i] = 0.f; }
#pragma unroll
    for (int dc = 0; dc < 4; ++dc) o[mr][dc] = f32x4{0.f, 0.f, 0.f, 0.f};
  }
  const float c1 = 0.18033688f;            // 0.125 * log2(e)

  // ---- prologue: prefetch tile 0's K and V fragments ----
  bf16x8 kf[4][2], vf[4][2];
#pragma unroll
  for (int c = 0; c < 4; ++c)
#pragma unroll
    for (int kk = 0; kk < 2; ++kk) {
      kf[c][kk] = *(const bf16x8*)(Kl + c * 1024 + kk * 32);
      vf[c][kk] = *(const bf16x8*)(Vl + c * 32768 + kk * 32);
    }

  for (int tk = 0; tk < nkv; ++tk) {
    const int kv0 = tk * 64;
    const int kvn = kv0 + 64;
    const bool more = (tk + 1 < nkv);
    // ---- S = Q K^T (32 q-rows x 64 kv) from prefetched kf ----
    f32x4 sc[2][4];
#pragma unroll
    for (int mr = 0; mr < 2; ++mr)
#pragma unroll
      for (int c = 0; c < 4; ++c) {
        f32x4 z = f32x4{0.f, 0.f, 0.f, 0.f};
        z = MFMA16(qf[mr][0], kf[c][0], z, 0, 0, 0);
        z = MFMA16(qf[mr][1], kf[c][1], z, 0, 0, 0);
        sc[mr][c] = z;
      }
    // ---- refill kf for tile t+1 (issue-early: lands during softmax+PV) ----
    if (more) {
#pragma unroll
      for (int c = 0; c < 4; ++c)
#pragma unroll
        for (int kk = 0; kk < 2; ++kk)
          kf[c][kk] = *(const bf16x8*)(Kl + (size_t)kvn * 64 + c * 1024 + kk * 32);
    }
    // ---- causal mask: only the last tile intersects the diagonal ----
    if (tk == nkv - 1) {
#pragma unroll
      for (int mr = 0; mr < 2; ++mr)
#pragma unroll
        for (int c = 0; c < 4; ++c)
#pragma unroll
          for (int i = 0; i < 4; ++i) {
            const int qa = q0 + mr * 16 + lhi * 4 + i;
            const int ka = kv0 + c * 16 + l15;
            sc[mr][c][i] = (ka <= qa) ? sc[mr][c][i] : -3.0e38f;
          }
    }
    // ---- tile row-max (in-lane over c, then 4 DPP steps across 16 lanes) ----
    float tm[2][4];
    bool need = false;
#pragma unroll
    for (int mr = 0; mr < 2; ++mr)
#pragma unroll
      for (int i = 0; i < 4; ++i) {
        float mx = fmaxf(fmaxf(sc[mr][0][i], sc[mr][1][i]),
                         fmaxf(sc[mr][2][i], sc[mr][3][i]));
        mx = rowmax16(mx) * c1;            // scaled (exp2) domain
        tm[mr][i] = mx;
        need |= (mx > m2[mr][i] + 11.5f);  // defer-max THR
      }
    if (__any(need)) {
#pragma unroll
      for (int mr = 0; mr < 2; ++mr)
#pragma unroll
        for (int i = 0; i < 4; ++i) {
          const float mn = fmaxf(m2[mr][i], tm[mr][i]);
          const float rs = vexp2(m2[mr][i] - mn);
          m2[mr][i] = mn;
          lp[mr][i] *= rs;
#pragma unroll
          for (int dc = 0; dc < 4; ++dc) o[mr][dc][i] *= rs;
        }
    }
    // ---- p = exp2(s*c1 - m2); per-lane partial sums; P -> LDS ----
#pragma unroll
    for (int mr = 0; mr < 2; ++mr)
#pragma unroll
      for (int i = 0; i < 4; ++i) {
        float psum = 0.f;
#pragma unroll
        for (int c = 0; c < 4; ++c) {
          const float p = vexp2(__builtin_fmaf(sc[mr][c][i], c1, -m2[mr][i]));
          psum += p;
          Plds[(mr * 16 + lhi * 4 + i) * 72 + c * 16 + l15] = f2bf(p);
        }
        lp[mr][i] += psum;
      }
    // ---- O += P V from prefetched vf ----
#pragma unroll
    for (int mr = 0; mr < 2; ++mr) {
      bf16x8 pf[2];
#pragma unroll
      for (int kk = 0; kk < 2; ++kk)
        pf[kk] = *(const bf16x8*)&Plds[(mr * 16 + l15) * 72 + kk * 32 + lhi * 8];
#pragma unroll
      for (int dc = 0; dc < 4; ++dc) {
        o[mr][dc] = MFMA16(pf[0], vf[dc][0], o[mr][dc], 0, 0, 0);
        o[mr][dc] = MFMA16(pf[1], vf[dc][1], o[mr][dc], 0, 0, 0);
      }
    }
    // ---- refill vf for tile t+1 (a full iteration to land) ----
    if (more) {
#pragma unroll
      for (int c = 0; c < 4; ++c)
#pragma unroll
        for (int kk = 0; kk < 2; ++kk)
          vf[c][kk] = *(const bf16x8*)(Vl + c * 32768 + kvn + kk * 32);
    }
  }

  // ---- epilogue: complete l across lanes (DPP), divide, store ----
#pragma unroll
  for (int mr = 0; mr < 2; ++mr)
#pragma unroll
    for (int i = 0; i < 4; ++i) {
      const float lfull = rowsum16(lp[mr][i]);
      const float inv = 1.0f / lfull;
      const int qa = q0 + mr * 16 + lhi * 4 + i;
#pragma unroll
      for (int dc = 0; dc < 4; ++dc) {
        const int d = dc * 16 + l15;
        ao[((size_t)(bb * 2048 + qa)) * 1280 + hh * 64 + d] = f2bf(o[mr][dc][i] * inv);
      }
    }
}

extern "C" void kernel_launch(void* const* d_in, const int* in_sizes, int n_in,
                              void* d_out, int out_size, void* d_ws, size_t ws_size,
                              hipStream_t stream) {
  (void)in_sizes; (void)n_in; (void)out_size; (void)ws_size;
  const float* x      = (const float*)d_in[0];
  const float* w_attn = (const float*)d_in[1];
  const float* b_attn = (const float*)d_in[2];
  const float* w_proj = (const float*)d_in[3];
  const float* b_proj = (const float*)d_in[4];
  float* out = (float*)d_out;

  char* ws = (char*)d_ws;
  u16* x_bf = (u16*)(ws + 0);              // 10485760 B; reused as vt after gemm_qkv
  u16* wa_t = (u16*)(ws + 10485760);       //  9830400 B
  u16* wp_t = (u16*)(ws + 20316160);       //  3276800 B
  u16* q_ws = (u16*)(ws + 23592960);       // 10485760 B
  u16* k_ws = (u16*)(ws + 34078720);       // 10485760 B
  u16* v_ws = (u16*)(ws + 44564480);       // 10485760 B; reused as ao after transpose_v
  u16* vt   = x_bf;
  u16* ao   = v_ws;

  k_cast<<<5120, 256, 0, stream>>>(x, x_bf, 4096 * 1280 / 4);
  k_transpose_cast<<<dim3(60, 20), 256, 0, stream>>>(w_attn, wa_t, 1280, 3840);
  k_transpose_cast<<<dim3(20, 20), 256, 0, stream>>>(w_proj, wp_t, 1280, 1280);
  k_gemm_qkv<<<dim3(32, 30), 256, 0, stream>>>(x_bf, wa_t, b_attn, q_ws, k_ws, v_ws);
  k_transpose_v<<<dim3(32, 40), 256, 0, stream>>>(v_ws, vt);
  k_attn5<<<dim3(40, 64), 64, 0, stream>>>(q_ws, k_ws, vt, ao);
  k_gemm_proj<<<dim3(32, 10), 256, 0, stream>>>(ao, wp_t, b_proj, out);
}